// Round 2
// baseline (911.389 us; speedup 1.0000x reference)
//
#include <hip/hip_runtime.h>

// Problem constants (fixed by the reference setup)
#define NN   2048   // N nodes
#define BATCH 8
#define FIN  16
#define TT   12
#define FOUT 32
#define FT   (FIN*TT)    // 192
#define OT   (FOUT*TT)   // 384

// ---------------------------------------------------------------------------
// Phase 1: S = softmax(relu(E E^T), axis=1)   (rows of S sum to 1)
// One block per row n; row staged in LDS.
// ---------------------------------------------------------------------------
__global__ __launch_bounds__(256)
void k_supports(const float* __restrict__ E, float* __restrict__ S) {
    const int n = blockIdx.x;
    __shared__ float row[NN];
    __shared__ float red[256];
    const int tid = threadIdx.x;

    float en[16];
    #pragma unroll
    for (int j = 0; j < 16; ++j) en[j] = E[n * 16 + j];

    float lmax = 0.0f;  // relu output >= 0
    for (int m = tid; m < NN; m += 256) {
        float d = 0.0f;
        #pragma unroll
        for (int j = 0; j < 16; ++j) d += en[j] * E[m * 16 + j];
        d = fmaxf(d, 0.0f);
        row[m] = d;
        lmax = fmaxf(lmax, d);
    }
    red[tid] = lmax; __syncthreads();
    for (int s = 128; s > 0; s >>= 1) {
        if (tid < s) red[tid] = fmaxf(red[tid], red[tid + s]);
        __syncthreads();
    }
    const float mx = red[0];
    __syncthreads();

    float lsum = 0.0f;
    for (int m = tid; m < NN; m += 256) {
        float e = __expf(row[m] - mx);
        row[m] = e;
        lsum += e;
    }
    red[tid] = lsum; __syncthreads();
    for (int s = 128; s > 0; s >>= 1) {
        if (tid < s) red[tid] += red[tid + s];
        __syncthreads();
    }
    const float inv = 1.0f / red[0];
    for (int m = tid; m < NN; m += 256) S[(size_t)n * NN + m] = row[m] * inv;
}

// ---------------------------------------------------------------------------
// Phase 2: T2 = 2 * S @ S - I      (2048^3 fp32 GEMM, 64x64 tile, BK=32)
// ---------------------------------------------------------------------------
__global__ __launch_bounds__(256)
void k_t2(const float* __restrict__ S, float* __restrict__ T2) {
    const int bx = blockIdx.x % (NN / 64);
    const int by = blockIdx.x / (NN / 64);
    const int m0 = bx * 64;
    const int n0 = by * 64;
    __shared__ float As[32][65];   // As[kk][i] = S[n0+i][l0+kk]
    __shared__ float Bs[32][65];   // Bs[kk][j] = S[l0+kk][m0+j]
    const int tid = threadIdx.x;
    const int tx = tid & 15, ty = tid >> 4;

    float acc[4][4];
    #pragma unroll
    for (int i = 0; i < 4; ++i)
        #pragma unroll
        for (int j = 0; j < 4; ++j) acc[i][j] = 0.0f;

    for (int l0 = 0; l0 < NN; l0 += 32) {
        {   // stage A (transposed into LDS): 64 rows x 32 cols
            const int r = tid >> 3;          // 0..31
            const int c = (tid & 7) * 4;     // 0..28
            #pragma unroll
            for (int p = 0; p < 2; ++p) {
                const int rr = r + 32 * p;
                const float4 v = *(const float4*)&S[(size_t)(n0 + rr) * NN + l0 + c];
                As[c + 0][rr] = v.x; As[c + 1][rr] = v.y;
                As[c + 2][rr] = v.z; As[c + 3][rr] = v.w;
            }
            // stage B: 32 rows x 64 cols
            const int kk = tid >> 3;         // 0..31
            const int c2 = (tid & 7) * 8;    // 0..56
            const float4 v0 = *(const float4*)&S[(size_t)(l0 + kk) * NN + m0 + c2];
            const float4 v1 = *(const float4*)&S[(size_t)(l0 + kk) * NN + m0 + c2 + 4];
            Bs[kk][c2 + 0] = v0.x; Bs[kk][c2 + 1] = v0.y;
            Bs[kk][c2 + 2] = v0.z; Bs[kk][c2 + 3] = v0.w;
            Bs[kk][c2 + 4] = v1.x; Bs[kk][c2 + 5] = v1.y;
            Bs[kk][c2 + 6] = v1.z; Bs[kk][c2 + 7] = v1.w;
        }
        __syncthreads();
        #pragma unroll
        for (int kk = 0; kk < 32; ++kk) {
            float a[4], b[4];
            #pragma unroll
            for (int i = 0; i < 4; ++i) a[i] = As[kk][ty * 4 + i];
            #pragma unroll
            for (int j = 0; j < 4; ++j) b[j] = Bs[kk][tx * 4 + j];
            #pragma unroll
            for (int i = 0; i < 4; ++i)
                #pragma unroll
                for (int j = 0; j < 4; ++j) acc[i][j] += a[i] * b[j];
        }
        __syncthreads();
    }
    #pragma unroll
    for (int i = 0; i < 4; ++i) {
        const int n = n0 + ty * 4 + i;
        #pragma unroll
        for (int j = 0; j < 4; ++j) {
            const int m = m0 + tx * 4 + j;
            T2[(size_t)n * NN + m] = 2.0f * acc[i][j] - (n == m ? 1.0f : 0.0f);
        }
    }
}

// ---------------------------------------------------------------------------
// Phase 3: rhs[k1][b][m][ft] = sum_n P[n,m]*att[b,n,m]*x[b,n,ft]
//          k1=0 -> P=S (k=1), k1=1 -> P=T2 (k=2).
// Block tile: 64 m x 192 ft, n-chunks of 32. Hadamard fused in staging.
// ---------------------------------------------------------------------------
__global__ __launch_bounds__(256)
void k_rhs(const float* __restrict__ S, const float* __restrict__ T2,
           const float* __restrict__ att, const float* __restrict__ x,
           float* __restrict__ rhs) {
    const int m0 = blockIdx.x * 64;
    const int b  = blockIdx.y;
    const int k1 = blockIdx.z;
    const float* __restrict__ P = k1 ? T2 : S;
    const float* __restrict__ attb = att + (size_t)b * NN * NN;
    const float* __restrict__ xb   = x + (size_t)b * NN * FT;

    __shared__ float Ws[32][68];     // Ws[nn][m']  (Hadamard product)
    __shared__ float Xs[32][200];    // Xs[nn][ft]

    const int tid = threadIdx.x;
    const int tx = tid & 15, ty = tid >> 4;

    float acc[12][4];
    #pragma unroll
    for (int j = 0; j < 12; ++j)
        #pragma unroll
        for (int i = 0; i < 4; ++i) acc[j][i] = 0.0f;

    for (int nc = 0; nc < NN; nc += 32) {
        // stage W: 32 x 64 = 2048 elements (8 per thread, float4-width groups)
        #pragma unroll
        for (int p = 0; p < 2; ++p) {
            const int id = tid + 256 * p;      // 0..511
            const int nn = id >> 4;            // 0..31
            const int mq = (id & 15) * 4;      // 0..60
            const float4 pv = *(const float4*)&P[(size_t)(nc + nn) * NN + m0 + mq];
            const float4 av = *(const float4*)&attb[(size_t)(nc + nn) * NN + m0 + mq];
            Ws[nn][mq + 0] = pv.x * av.x;
            Ws[nn][mq + 1] = pv.y * av.y;
            Ws[nn][mq + 2] = pv.z * av.z;
            Ws[nn][mq + 3] = pv.w * av.w;
        }
        // stage X: 32 x 192 = 6144 elements (24 per thread)
        #pragma unroll
        for (int p = 0; p < 6; ++p) {
            const int id = tid + 256 * p;      // 0..1535
            const int nn = id / 48;            // 0..31
            const int fq = (id % 48) * 4;      // 0..188
            const float4 xv = *(const float4*)&xb[(size_t)(nc + nn) * FT + fq];
            Xs[nn][fq + 0] = xv.x;
            Xs[nn][fq + 1] = xv.y;
            Xs[nn][fq + 2] = xv.z;
            Xs[nn][fq + 3] = xv.w;
        }
        __syncthreads();
        #pragma unroll 8
        for (int nn = 0; nn < 32; ++nn) {
            float w[4];
            #pragma unroll
            for (int i = 0; i < 4; ++i) w[i] = Ws[nn][tx * 4 + i];
            float xv[12];
            #pragma unroll
            for (int j = 0; j < 12; ++j) xv[j] = Xs[nn][ty * 12 + j];
            #pragma unroll
            for (int j = 0; j < 12; ++j)
                #pragma unroll
                for (int i = 0; i < 4; ++i) acc[j][i] += xv[j] * w[i];
        }
        __syncthreads();
    }
    float* __restrict__ outp = rhs + ((size_t)k1 * BATCH + b) * NN * FT;
    #pragma unroll
    for (int i = 0; i < 4; ++i) {
        const int m = m0 + tx * 4 + i;
        #pragma unroll
        for (int j = 0; j < 12; ++j)
            outp[(size_t)m * FT + ty * 12 + j] = acc[j][i];
    }
}

// ---------------------------------------------------------------------------
// Phase 4: out[b,m,o,t] = relu( sum_f th0[f,o]*att[b,m,m]*x[b,m,f,t]
//                              + th1[f,o]*rhs1[b,m,f,t] + th2[f,o]*rhs2[b,m,f,t] )
// One block per (b,m).
// ---------------------------------------------------------------------------
__global__ __launch_bounds__(128)
void k_out(const float* __restrict__ x, const float* __restrict__ att,
           const float* __restrict__ theta, const float* __restrict__ rhs,
           float* __restrict__ out) {
    const int m = blockIdx.x & (NN - 1);
    const int b = blockIdx.x >> 11;
    __shared__ float xr[FT], r1[FT], r2[FT];
    __shared__ float th[3 * FIN * FOUT];   // 1536
    const int tid = threadIdx.x;

    const float* __restrict__ xb = x + ((size_t)b * NN + m) * FT;
    const float* __restrict__ p1 = rhs + ((size_t)0 * BATCH + b) * NN * FT + (size_t)m * FT;
    const float* __restrict__ p2 = rhs + ((size_t)1 * BATCH + b) * NN * FT + (size_t)m * FT;
    const float a0 = att[((size_t)b * NN + m) * NN + m];

    for (int i = tid; i < FT; i += 128) {
        xr[i] = xb[i] * a0;
        r1[i] = p1[i];
        r2[i] = p2[i];
    }
    for (int i = tid; i < 3 * FIN * FOUT; i += 128) th[i] = theta[i];
    __syncthreads();

    float* __restrict__ ob = out + ((size_t)b * NN + m) * OT;
    for (int idx = tid; idx < OT; idx += 128) {
        const int o = idx / TT, t = idx % TT;
        float acc = 0.0f;
        #pragma unroll
        for (int f = 0; f < FIN; ++f) {
            const int ft = f * TT + t;
            acc += th[f * FOUT + o] * xr[ft];
            acc += th[512 + f * FOUT + o] * r1[ft];
            acc += th[1024 + f * FOUT + o] * r2[ft];
        }
        ob[idx] = fmaxf(acc, 0.0f);
    }
}

// ---------------------------------------------------------------------------
extern "C" void kernel_launch(void* const* d_in, const int* in_sizes, int n_in,
                              void* d_out, int out_size, void* d_ws, size_t ws_size,
                              hipStream_t stream) {
    const float* x     = (const float*)d_in[0]; // (B,N,F_in,T) fp32
    const float* att   = (const float*)d_in[1]; // (B,N,N) fp32
    const float* E     = (const float*)d_in[2]; // (N,16) fp32
    const float* theta = (const float*)d_in[3]; // (K,F_in,F_out) fp32
    float* out = (float*)d_out;                 // (B,N,F_out,T) fp32

    // Workspace layout (fp32): S[N*N] | T2[N*N] | rhs[2*B*N*FT]   ~ 59 MB
    float* S   = (float*)d_ws;
    float* T2  = S + (size_t)NN * NN;
    float* rhs = T2 + (size_t)NN * NN;

    k_supports<<<NN, 256, 0, stream>>>(E, S);
    k_t2<<<dim3((NN / 64) * (NN / 64)), 256, 0, stream>>>(S, T2);
    k_rhs<<<dim3(NN / 64, BATCH, 2), 256, 0, stream>>>(S, T2, att, x, rhs);
    k_out<<<BATCH * NN, 128, 0, stream>>>(x, att, theta, rhs, out);
}

// Round 4
// 352.670 us; speedup vs baseline: 2.5843x; 2.5843x over previous
//
#include <hip/hip_runtime.h>

// Problem constants (fixed by the reference setup)
#define NN    2048
#define BATCH 8
#define FIN   16
#define TT    12
#define FOUT  32
#define FT    (FIN*TT)    // 192
#define OT    (FOUT*TT)   // 384

typedef unsigned short ushort_t;
typedef __attribute__((ext_vector_type(8))) short   short8;
typedef __attribute__((ext_vector_type(4))) float   f32x4;
typedef __attribute__((ext_vector_type(4))) unsigned short us4;
typedef __attribute__((ext_vector_type(8))) unsigned short us8;

__device__ __forceinline__ float b2f(unsigned short u) {
    union { unsigned int i; float f; } v; v.i = ((unsigned int)u) << 16; return v.f;
}
__device__ __forceinline__ unsigned short f2b(float f) {
    union { float f; unsigned int i; } v; v.f = f;
    unsigned int x = v.i;
    x += 0x7fffu + ((x >> 16) & 1u);   // RTNE
    return (unsigned short)(x >> 16);
}

// ---------------------------------------------------------------------------
// Phase 1: S = softmax(relu(E E^T), axis=1), written directly as bf16 (Sb)
// ---------------------------------------------------------------------------
__global__ __launch_bounds__(256)
void k_supports(const float* __restrict__ E, ushort_t* __restrict__ Sb) {
    const int n = blockIdx.x;
    __shared__ float row[NN];
    __shared__ float red[256];
    const int tid = threadIdx.x;

    float en[16];
    #pragma unroll
    for (int j = 0; j < 16; ++j) en[j] = E[n * 16 + j];

    float lmax = 0.0f;  // relu output >= 0
    for (int m = tid; m < NN; m += 256) {
        float d = 0.0f;
        #pragma unroll
        for (int j = 0; j < 16; ++j) d += en[j] * E[m * 16 + j];
        d = fmaxf(d, 0.0f);
        row[m] = d;
        lmax = fmaxf(lmax, d);
    }
    red[tid] = lmax; __syncthreads();
    for (int s = 128; s > 0; s >>= 1) {
        if (tid < s) red[tid] = fmaxf(red[tid], red[tid + s]);
        __syncthreads();
    }
    const float mx = red[0];
    __syncthreads();

    float lsum = 0.0f;
    for (int m = tid; m < NN; m += 256) {
        float e = __expf(row[m] - mx);
        row[m] = e;
        lsum += e;
    }
    red[tid] = lsum; __syncthreads();
    for (int s = 128; s > 0; s >>= 1) {
        if (tid < s) red[tid] += red[tid + s];
        __syncthreads();
    }
    const float inv = 1.0f / red[0];
    for (int m = tid; m < NN; m += 256) Sb[(size_t)n * NN + m] = f2b(row[m] * inv);
}

// ---------------------------------------------------------------------------
// Pack: SbT[m][n] = Sb[n][m]   (tile transpose, bf16)
// ---------------------------------------------------------------------------
__global__ __launch_bounds__(256)
void k_pack_st(const ushort_t* __restrict__ Sb, ushort_t* __restrict__ SbT) {
    const int r0 = blockIdx.x * 64, c0 = blockIdx.y * 64;
    __shared__ ushort_t Lt[64][65];
    const int tid = threadIdx.x;
    #pragma unroll
    for (int p = 0; p < 2; ++p) {
        const int i = (tid >> 3) + p * 32;
        const int j8 = (tid & 7) * 8;
        us8 v = *(const us8*)&Sb[(size_t)(r0 + i) * NN + c0 + j8];
        #pragma unroll
        for (int e = 0; e < 8; ++e) Lt[i][j8 + e] = v[e];
    }
    __syncthreads();
    #pragma unroll
    for (int p = 0; p < 2; ++p) {
        const int jj = (tid >> 3) + p * 32;
        const int i8 = (tid & 7) * 8;
        us8 v;
        #pragma unroll
        for (int e = 0; e < 8; ++e) v[e] = Lt[i8 + e][jj];
        *(us8*)&SbT[(size_t)(c0 + jj) * NN + r0 + i8] = v;
    }
}

// ---------------------------------------------------------------------------
// Pack: xbT[b][ft][n] = bf16(x[b][n][ft])   (per-batch transpose)
// ---------------------------------------------------------------------------
__global__ __launch_bounds__(256)
void k_pack_x(const float* __restrict__ x, ushort_t* __restrict__ xbT) {
    const int nc = blockIdx.x * 64;
    const int b  = blockIdx.y;
    __shared__ ushort_t Lt[FT][65];
    const int tid = threadIdx.x;
    const float* __restrict__ xb = x + (size_t)b * NN * FT;
    #pragma unroll
    for (int p = 0; p < 12; ++p) {
        const int id = tid + 256 * p;      // 0..3071
        const int nn = id / 48;
        const int f4 = (id % 48) * 4;
        const float4 v = *(const float4*)&xb[(size_t)(nc + nn) * FT + f4];
        Lt[f4 + 0][nn] = f2b(v.x);
        Lt[f4 + 1][nn] = f2b(v.y);
        Lt[f4 + 2][nn] = f2b(v.z);
        Lt[f4 + 3][nn] = f2b(v.w);
    }
    __syncthreads();
    #pragma unroll
    for (int p = 0; p < 6; ++p) {
        const int id = tid + 256 * p;      // 0..1535
        const int ft = id >> 3;
        const int n8 = (id & 7) * 8;
        us8 v;
        #pragma unroll
        for (int e = 0; e < 8; ++e) v[e] = Lt[ft][n8 + e];
        *(us8*)&xbT[((size_t)b * FT + ft) * NN + nc + n8] = v;
    }
}

// ---------------------------------------------------------------------------
// Phase 2: T2b = bf16(2*S@S - I). MFMA bf16, 128(n) x 64(m) tile, BK=64.
// Staging: us8 global loads -> VGPR -> ds_write_b128, XOR-swizzled chunks
// (LDS[row][c] holds global chunk c ^ (row&7)).
// ---------------------------------------------------------------------------
__global__ __launch_bounds__(256)
void k_t2(const ushort_t* __restrict__ Sb, const ushort_t* __restrict__ SbT,
          ushort_t* __restrict__ T2b) {
    const int m0 = blockIdx.x * 64;     // cols
    const int n0 = blockIdx.y * 128;    // rows
    __shared__ __align__(16) ushort_t As[128 * 64];
    __shared__ __align__(16) ushort_t Bs[64 * 64];
    const int tid = threadIdx.x;
    const int lane = tid & 63, w = tid >> 6;
    const int l15 = lane & 15, q = lane >> 4, l7 = lane & 7, l3 = lane >> 3;
    const int n0w = (w & 1) * 64, c0w = (w >> 1) * 32;

    f32x4 acc[4][2];
    #pragma unroll
    for (int i = 0; i < 4; ++i)
        #pragma unroll
        for (int j = 0; j < 2; ++j) acc[i][j] = {0.f, 0.f, 0.f, 0.f};

    for (int l0 = 0; l0 < NN; l0 += 64) {
        us8 av[4], bv[2];
        #pragma unroll
        for (int p = 0; p < 4; ++p) {                 // A: rows of Sb
            const int row = w * 32 + p * 8 + l3;
            av[p] = *(const us8*)&Sb[(size_t)(n0 + row) * NN + l0 + l7 * 8];
        }
        #pragma unroll
        for (int p = 0; p < 2; ++p) {                 // B: rows of SbT
            const int row = w * 16 + p * 8 + l3;
            bv[p] = *(const us8*)&SbT[(size_t)(m0 + row) * NN + l0 + l7 * 8];
        }
        __syncthreads();   // prev-iter LDS reads done
        #pragma unroll
        for (int p = 0; p < 4; ++p) {
            const int row = w * 32 + p * 8 + l3;
            *(us8*)&As[row * 64 + (l7 ^ l3) * 8] = av[p];
        }
        #pragma unroll
        for (int p = 0; p < 2; ++p) {
            const int row = w * 16 + p * 8 + l3;
            *(us8*)&Bs[row * 64 + (l7 ^ l3) * 8] = bv[p];
        }
        __syncthreads();
        #pragma unroll
        for (int s = 0; s < 2; ++s) {
            short8 a[4], bb[2];
            const int u = (s * 4 + q) ^ l7;           // row&7 == l15&7 == l7
            #pragma unroll
            for (int i = 0; i < 4; ++i) {
                const int row = n0w + i * 16 + l15;
                a[i] = *(const short8*)&As[row * 64 + u * 8];
            }
            #pragma unroll
            for (int j = 0; j < 2; ++j) {
                const int col = c0w + j * 16 + l15;
                bb[j] = *(const short8*)&Bs[col * 64 + u * 8];
            }
            #pragma unroll
            for (int i = 0; i < 4; ++i)
                #pragma unroll
                for (int j = 0; j < 2; ++j)
                    acc[i][j] = __builtin_amdgcn_mfma_f32_16x16x32_bf16(a[i], bb[j], acc[i][j], 0, 0, 0);
        }
    }
    #pragma unroll
    for (int i = 0; i < 4; ++i)
        #pragma unroll
        for (int j = 0; j < 2; ++j)
            #pragma unroll
            for (int r = 0; r < 4; ++r) {
                const int ng = n0 + n0w + i * 16 + q * 4 + r;
                const int mg = m0 + c0w + j * 16 + l15;
                const float v = 2.0f * acc[i][j][r] - (ng == mg ? 1.0f : 0.0f);
                T2b[(size_t)ng * NN + mg] = f2b(v);
            }
}

// ---------------------------------------------------------------------------
// Phase 3: rhs[k1][b][m][ft] = sum_n (P_k1 . att_b)[n,m] * x[b,n,ft]  (MFMA)
// Block: 32 m x 192 ft, BOTH k1 fused (att read once). BK=64.
// Waves: w&1 = k1, w>>1 = ft-half. W=P*att staged via VALU into padded LDS
// (transposed, pitch 72); X staged via us8->ds_write (swizzled).
// ---------------------------------------------------------------------------
__global__ __launch_bounds__(256)
void k_rhs(const ushort_t* __restrict__ Sb, const ushort_t* __restrict__ T2b,
           const float* __restrict__ att, const ushort_t* __restrict__ xbT,
           float* __restrict__ rhs) {
    const int m0 = blockIdx.x * 32;
    const int b  = blockIdx.y;
    __shared__ __align__(16) ushort_t As[2 * 32 * 72];
    __shared__ __align__(16) ushort_t Xs[FT * 64];
    const int tid = threadIdx.x;
    const int lane = tid & 63, w = tid >> 6;
    const int l15 = lane & 15, q = lane >> 4, l7 = lane & 7, l3 = lane >> 3;
    const int k1 = w & 1, ft0 = (w >> 1) * 96;
    const float* __restrict__ attb = att + (size_t)b * NN * NN;

    // W-staging assignment: half-block per k1; 8 m-groups x 16 nn-groups
    const int k1s = tid >> 7;
    const int uu  = tid & 127;
    const int m4  = (uu & 7) * 4;
    const int nn4 = (uu >> 3) * 4;
    const ushort_t* __restrict__ Pk = k1s ? T2b : Sb;

    f32x4 acc[2][6];
    #pragma unroll
    for (int i = 0; i < 2; ++i)
        #pragma unroll
        for (int t = 0; t < 6; ++t) acc[i][t] = {0.f, 0.f, 0.f, 0.f};

    for (int nc = 0; nc < NN; nc += 64) {
        us8 xv[6];
        #pragma unroll
        for (int p = 0; p < 6; ++p) {                 // X: rows of xbT
            const int row = (w * 6 + p) * 8 + l3;
            xv[p] = *(const us8*)&xbT[((size_t)b * FT + row) * NN + nc + l7 * 8];
        }
        ushort_t Wv[4][4];                            // W = bf16(P*att)
        #pragma unroll
        for (int r = 0; r < 4; ++r) {
            const int nn = nc + nn4 + r;
            const us4    pv = *(const us4*)&Pk[(size_t)nn * NN + m0 + m4];
            const float4 av = *(const float4*)&attb[(size_t)nn * NN + m0 + m4];
            Wv[r][0] = f2b(b2f(pv.x) * av.x);
            Wv[r][1] = f2b(b2f(pv.y) * av.y);
            Wv[r][2] = f2b(b2f(pv.z) * av.z);
            Wv[r][3] = f2b(b2f(pv.w) * av.w);
        }
        __syncthreads();   // prev-iter LDS reads done
        #pragma unroll
        for (int p = 0; p < 6; ++p) {
            const int row = (w * 6 + p) * 8 + l3;
            *(us8*)&Xs[row * 64 + (l7 ^ l3) * 8] = xv[p];
        }
        #pragma unroll
        for (int c = 0; c < 4; ++c) {                 // transposed: As[k1][m][nn]
            us4 wv = {Wv[0][c], Wv[1][c], Wv[2][c], Wv[3][c]};
            *(us4*)&As[(k1s * 32 + m4 + c) * 72 + nn4] = wv;
        }
        __syncthreads();
        #pragma unroll
        for (int s = 0; s < 2; ++s) {
            short8 a[2], bb[6];
            #pragma unroll
            for (int i = 0; i < 2; ++i) {
                const int row = i * 16 + l15;
                a[i] = *(const short8*)&As[(k1 * 32 + row) * 72 + s * 32 + q * 8];
            }
            #pragma unroll
            for (int t = 0; t < 6; ++t) {
                const int col = ft0 + t * 16 + l15;
                const int u = (s * 4 + q) ^ (col & 7);
                bb[t] = *(const short8*)&Xs[col * 64 + u * 8];
            }
            #pragma unroll
            for (int i = 0; i < 2; ++i)
                #pragma unroll
                for (int t = 0; t < 6; ++t)
                    acc[i][t] = __builtin_amdgcn_mfma_f32_16x16x32_bf16(a[i], bb[t], acc[i][t], 0, 0, 0);
        }
    }
    float* __restrict__ op = rhs + ((size_t)(k1 * BATCH + b)) * NN * FT;
    #pragma unroll
    for (int i = 0; i < 2; ++i)
        #pragma unroll
        for (int t = 0; t < 6; ++t)
            #pragma unroll
            for (int r = 0; r < 4; ++r) {
                const int mg = m0 + i * 16 + q * 4 + r;
                const int ftg = ft0 + t * 16 + l15;
                op[(size_t)mg * FT + ftg] = acc[i][t][r];
            }
}

// ---------------------------------------------------------------------------
// Phase 4: out[b,m,o,t] = relu( th0.(att[b,m,m]*x[b,m]) + th1.rhs1 + th2.rhs2 )
// ---------------------------------------------------------------------------
__global__ __launch_bounds__(128)
void k_out(const float* __restrict__ x, const float* __restrict__ att,
           const float* __restrict__ theta, const float* __restrict__ rhs,
           float* __restrict__ out) {
    const int m = blockIdx.x & (NN - 1);
    const int b = blockIdx.x >> 11;
    __shared__ float xr[FT], r1[FT], r2[FT];
    __shared__ float th[3 * FIN * FOUT];
    const int tid = threadIdx.x;

    const float* __restrict__ xb = x + ((size_t)b * NN + m) * FT;
    const float* __restrict__ p1 = rhs + ((size_t)0 * BATCH + b) * NN * FT + (size_t)m * FT;
    const float* __restrict__ p2 = rhs + ((size_t)1 * BATCH + b) * NN * FT + (size_t)m * FT;
    const float a0 = att[((size_t)b * NN + m) * NN + m];

    for (int i = tid; i < FT; i += 128) {
        xr[i] = xb[i] * a0;
        r1[i] = p1[i];
        r2[i] = p2[i];
    }
    for (int i = tid; i < 3 * FIN * FOUT; i += 128) th[i] = theta[i];
    __syncthreads();

    float* __restrict__ ob = out + ((size_t)b * NN + m) * OT;
    for (int idx = tid; idx < OT; idx += 128) {
        const int o = idx / TT, t = idx % TT;
        float acc = 0.0f;
        #pragma unroll
        for (int f = 0; f < FIN; ++f) {
            const int ft = f * TT + t;
            acc += th[f * FOUT + o] * xr[ft];
            acc += th[512 + f * FOUT + o] * r1[ft];
            acc += th[1024 + f * FOUT + o] * r2[ft];
        }
        ob[idx] = fmaxf(acc, 0.0f);
    }
}

// ---------------------------------------------------------------------------
extern "C" void kernel_launch(void* const* d_in, const int* in_sizes, int n_in,
                              void* d_out, int out_size, void* d_ws, size_t ws_size,
                              hipStream_t stream) {
    const float* x     = (const float*)d_in[0]; // (B,N,F_in,T) fp32
    const float* att   = (const float*)d_in[1]; // (B,N,N) fp32
    const float* E     = (const float*)d_in[2]; // (N,16) fp32
    const float* theta = (const float*)d_in[3]; // (K,F_in,F_out) fp32
    float* out = (float*)d_out;                 // (B,N,F_out,T) fp32

    // Workspace: Sb | SbT | T2b (bf16 N*N each) | xbT (bf16 B*FT*N) | rhs (fp32)
    ushort_t* Sb  = (ushort_t*)d_ws;
    ushort_t* SbT = Sb  + (size_t)NN * NN;
    ushort_t* T2b = SbT + (size_t)NN * NN;
    ushort_t* xbT = T2b + (size_t)NN * NN;
    float*    rhs = (float*)(xbT + (size_t)BATCH * FT * NN);   // ~54 MB total

    k_supports<<<NN, 256, 0, stream>>>(E, Sb);
    k_pack_st<<<dim3(32, 32), 256, 0, stream>>>(Sb, SbT);
    k_pack_x<<<dim3(32, BATCH), 256, 0, stream>>>(x, xbT);
    k_t2<<<dim3(32, 16), 256, 0, stream>>>(Sb, SbT, T2b);
    k_rhs<<<dim3(64, BATCH), 256, 0, stream>>>(Sb, T2b, att, xbT, rhs);
    k_out<<<BATCH * NN, 128, 0, stream>>>(x, att, theta, rhs, out);
}

// Round 5
// 335.162 us; speedup vs baseline: 2.7193x; 1.0522x over previous
//
#include <hip/hip_runtime.h>

// Problem constants (fixed by the reference setup)
#define NN    2048
#define BATCH 8
#define FIN   16
#define TT    12
#define FOUT  32
#define FT    (FIN*TT)    // 192
#define OT    (FOUT*TT)   // 384

typedef unsigned short ushort_t;
typedef __attribute__((ext_vector_type(8))) short   short8;
typedef __attribute__((ext_vector_type(4))) float   f32x4;
typedef __attribute__((ext_vector_type(4))) unsigned short us4;
typedef __attribute__((ext_vector_type(8))) unsigned short us8;

__device__ __forceinline__ float b2f(unsigned short u) {
    union { unsigned int i; float f; } v; v.i = ((unsigned int)u) << 16; return v.f;
}
__device__ __forceinline__ unsigned short f2b(float f) {
    union { float f; unsigned int i; } v; v.f = f;
    unsigned int x = v.i;
    x += 0x7fffu + ((x >> 16) & 1u);   // RTNE
    return (unsigned short)(x >> 16);
}

// ---------------------------------------------------------------------------
// Phase 1: S = softmax(relu(E E^T), axis=1), written directly as bf16 (Sb)
// ---------------------------------------------------------------------------
__global__ __launch_bounds__(256)
void k_supports(const float* __restrict__ E, ushort_t* __restrict__ Sb) {
    const int n = blockIdx.x;
    __shared__ float row[NN];
    __shared__ float red[256];
    const int tid = threadIdx.x;

    float en[16];
    #pragma unroll
    for (int j = 0; j < 16; ++j) en[j] = E[n * 16 + j];

    float lmax = 0.0f;  // relu output >= 0
    for (int m = tid; m < NN; m += 256) {
        float d = 0.0f;
        #pragma unroll
        for (int j = 0; j < 16; ++j) d += en[j] * E[m * 16 + j];
        d = fmaxf(d, 0.0f);
        row[m] = d;
        lmax = fmaxf(lmax, d);
    }
    red[tid] = lmax; __syncthreads();
    for (int s = 128; s > 0; s >>= 1) {
        if (tid < s) red[tid] = fmaxf(red[tid], red[tid + s]);
        __syncthreads();
    }
    const float mx = red[0];
    __syncthreads();

    float lsum = 0.0f;
    for (int m = tid; m < NN; m += 256) {
        float e = __expf(row[m] - mx);
        row[m] = e;
        lsum += e;
    }
    red[tid] = lsum; __syncthreads();
    for (int s = 128; s > 0; s >>= 1) {
        if (tid < s) red[tid] += red[tid + s];
        __syncthreads();
    }
    const float inv = 1.0f / red[0];
    for (int m = tid; m < NN; m += 256) Sb[(size_t)n * NN + m] = f2b(row[m] * inv);
}

// ---------------------------------------------------------------------------
// Pack: SbT[m][n] = Sb[n][m]   (tile transpose, bf16)
// ---------------------------------------------------------------------------
__global__ __launch_bounds__(256)
void k_pack_st(const ushort_t* __restrict__ Sb, ushort_t* __restrict__ SbT) {
    const int r0 = blockIdx.x * 64, c0 = blockIdx.y * 64;
    __shared__ ushort_t Lt[64][65];
    const int tid = threadIdx.x;
    #pragma unroll
    for (int p = 0; p < 2; ++p) {
        const int i = (tid >> 3) + p * 32;
        const int j8 = (tid & 7) * 8;
        us8 v = *(const us8*)&Sb[(size_t)(r0 + i) * NN + c0 + j8];
        #pragma unroll
        for (int e = 0; e < 8; ++e) Lt[i][j8 + e] = v[e];
    }
    __syncthreads();
    #pragma unroll
    for (int p = 0; p < 2; ++p) {
        const int jj = (tid >> 3) + p * 32;
        const int i8 = (tid & 7) * 8;
        us8 v;
        #pragma unroll
        for (int e = 0; e < 8; ++e) v[e] = Lt[i8 + e][jj];
        *(us8*)&SbT[(size_t)(c0 + jj) * NN + r0 + i8] = v;
    }
}

// ---------------------------------------------------------------------------
// Pack: xbT[b][ft][n] = bf16(x[b][n][ft])   (per-batch transpose)
// ---------------------------------------------------------------------------
__global__ __launch_bounds__(256)
void k_pack_x(const float* __restrict__ x, ushort_t* __restrict__ xbT) {
    const int nc = blockIdx.x * 64;
    const int b  = blockIdx.y;
    __shared__ ushort_t Lt[FT][65];
    const int tid = threadIdx.x;
    const float* __restrict__ xb = x + (size_t)b * NN * FT;
    #pragma unroll
    for (int p = 0; p < 12; ++p) {
        const int id = tid + 256 * p;      // 0..3071
        const int nn = id / 48;
        const int f4 = (id % 48) * 4;
        const float4 v = *(const float4*)&xb[(size_t)(nc + nn) * FT + f4];
        Lt[f4 + 0][nn] = f2b(v.x);
        Lt[f4 + 1][nn] = f2b(v.y);
        Lt[f4 + 2][nn] = f2b(v.z);
        Lt[f4 + 3][nn] = f2b(v.w);
    }
    __syncthreads();
    #pragma unroll
    for (int p = 0; p < 6; ++p) {
        const int id = tid + 256 * p;      // 0..1535
        const int ft = id >> 3;
        const int n8 = (id & 7) * 8;
        us8 v;
        #pragma unroll
        for (int e = 0; e < 8; ++e) v[e] = Lt[ft][n8 + e];
        *(us8*)&xbT[((size_t)b * FT + ft) * NN + nc + n8] = v;
    }
}

// ---------------------------------------------------------------------------
// Phase 2: T2b = bf16(2*S@S - I). MFMA bf16, 64x64 tile, BK=64,
// LDS double-buffered, one barrier per K-iter (loads overlap MFMA).
// ---------------------------------------------------------------------------
__global__ __launch_bounds__(256)
void k_t2(const ushort_t* __restrict__ Sb, const ushort_t* __restrict__ SbT,
          ushort_t* __restrict__ T2b) {
    const int m0 = blockIdx.x * 64;     // cols
    const int n0 = blockIdx.y * 64;     // rows
    __shared__ __align__(16) ushort_t As[2][64 * 64];
    __shared__ __align__(16) ushort_t Bs[2][64 * 64];
    const int tid = threadIdx.x;
    const int lane = tid & 63, w = tid >> 6;
    const int l15 = lane & 15, q = lane >> 4, l7 = lane & 7;
    const int n0w = (w & 1) * 32, m0w = (w >> 1) * 32;
    const int sr = tid >> 3;            // staging row 0..31 (+32)
    const int sc = tid & 7;             // staging chunk 0..7

    f32x4 acc[2][2];
    #pragma unroll
    for (int i = 0; i < 2; ++i)
        #pragma unroll
        for (int j = 0; j < 2; ++j) acc[i][j] = {0.f, 0.f, 0.f, 0.f};

    us8 av[2], bv[2];
    #pragma unroll
    for (int p = 0; p < 2; ++p) {       // prologue: K-chunk 0
        const int row = sr + 32 * p;
        av[p] = *(const us8*)&Sb[(size_t)(n0 + row) * NN + sc * 8];
        bv[p] = *(const us8*)&SbT[(size_t)(m0 + row) * NN + sc * 8];
    }
    #pragma unroll
    for (int p = 0; p < 2; ++p) {
        const int row = sr + 32 * p;
        const int cs = (sc ^ (row & 7)) * 8;
        *(us8*)&As[0][row * 64 + cs] = av[p];
        *(us8*)&Bs[0][row * 64 + cs] = bv[p];
    }
    for (int it = 0; it < 32; ++it) {
        __syncthreads();
        const int cur = it & 1;
        if (it < 31) {                  // prefetch next K-chunk (raw, no VALU dep)
            const int l0 = (it + 1) * 64;
            #pragma unroll
            for (int p = 0; p < 2; ++p) {
                const int row = sr + 32 * p;
                av[p] = *(const us8*)&Sb[(size_t)(n0 + row) * NN + l0 + sc * 8];
                bv[p] = *(const us8*)&SbT[(size_t)(m0 + row) * NN + l0 + sc * 8];
            }
        }
        #pragma unroll
        for (int s = 0; s < 2; ++s) {
            short8 a[2], bb[2];
            const int u = ((s * 4 + q) ^ l7) * 8;
            #pragma unroll
            for (int i = 0; i < 2; ++i)
                a[i] = *(const short8*)&As[cur][(n0w + i * 16 + l15) * 64 + u];
            #pragma unroll
            for (int j = 0; j < 2; ++j)
                bb[j] = *(const short8*)&Bs[cur][(m0w + j * 16 + l15) * 64 + u];
            #pragma unroll
            for (int i = 0; i < 2; ++i)
                #pragma unroll
                for (int j = 0; j < 2; ++j)
                    acc[i][j] = __builtin_amdgcn_mfma_f32_16x16x32_bf16(a[i], bb[j], acc[i][j], 0, 0, 0);
        }
        if (it < 31) {                  // write prefetched chunk to other buffer
            const int nxt = cur ^ 1;
            #pragma unroll
            for (int p = 0; p < 2; ++p) {
                const int row = sr + 32 * p;
                const int cs = (sc ^ (row & 7)) * 8;
                *(us8*)&As[nxt][row * 64 + cs] = av[p];
                *(us8*)&Bs[nxt][row * 64 + cs] = bv[p];
            }
        }
    }
    #pragma unroll
    for (int i = 0; i < 2; ++i)
        #pragma unroll
        for (int j = 0; j < 2; ++j)
            #pragma unroll
            for (int r = 0; r < 4; ++r) {
                const int ng = n0 + n0w + i * 16 + q * 4 + r;
                const int mg = m0 + m0w + j * 16 + l15;
                const float v = 2.0f * acc[i][j][r] - (ng == mg ? 1.0f : 0.0f);
                T2b[(size_t)ng * NN + mg] = f2b(v);
            }
}

// ---------------------------------------------------------------------------
// Phase 3: rhs[k1][b][m][ft] = sum_n (P_k1 . att_b)[n,m] * x[b,n,ft]  (MFMA)
// Block: 32 m x 192 ft, BOTH k1 fused (att read once). BK=64.
// LDS double-buffered (64 KB exactly), one barrier per iter; W Hadamard VALU
// deferred to the write phase so prefetch loads stay independent.
// ---------------------------------------------------------------------------
__global__ __launch_bounds__(256)
void k_rhs(const ushort_t* __restrict__ Sb, const ushort_t* __restrict__ T2b,
           const float* __restrict__ att, const ushort_t* __restrict__ xbT,
           float* __restrict__ rhs) {
    const int m0 = blockIdx.x * 32;
    const int b  = blockIdx.y;
    __shared__ __align__(16) ushort_t As[2][2 * 32 * 64];  // 16 KB: [buf][k1][m][nn swz]
    __shared__ __align__(16) ushort_t Xs[2][FT * 64];      // 48 KB
    const int tid = threadIdx.x;
    const int lane = tid & 63, w = tid >> 6;
    const int l15 = lane & 15, q = lane >> 4, l7 = lane & 7, l3 = lane >> 3;
    const int k1 = w & 1, ft0 = (w >> 1) * 96;
    const float* __restrict__ attb = att + (size_t)b * NN * NN;

    // W-staging assignment: half-block per k1; 8 m-groups x 16 nn-groups
    const int k1s = tid >> 7;
    const int uu  = tid & 127;
    const int m4  = (uu & 7) * 4;
    const int nn4 = (uu >> 3) * 4;
    const ushort_t* __restrict__ Pk = k1s ? T2b : Sb;

    f32x4 acc[2][6];
    #pragma unroll
    for (int i = 0; i < 2; ++i)
        #pragma unroll
        for (int t = 0; t < 6; ++t) acc[i][t] = {0.f, 0.f, 0.f, 0.f};

    us8   xv[6];
    us4   pv[4];
    f32x4 av4[4];

    // ---- prologue: nc = 0 ----
    #pragma unroll
    for (int p = 0; p < 6; ++p) {
        const int row = (w * 6 + p) * 8 + l3;
        xv[p] = *(const us8*)&xbT[((size_t)b * FT + row) * NN + l7 * 8];
    }
    #pragma unroll
    for (int r = 0; r < 4; ++r) {
        const int nn = nn4 + r;
        pv[r]  = *(const us4*)&Pk[(size_t)nn * NN + m0 + m4];
        av4[r] = *(const f32x4*)&attb[(size_t)nn * NN + m0 + m4];
    }
    #pragma unroll
    for (int p = 0; p < 6; ++p) {
        const int row = (w * 6 + p) * 8 + l3;
        *(us8*)&Xs[0][row * 64 + (l7 ^ l3) * 8] = xv[p];
    }
    #pragma unroll
    for (int c = 0; c < 4; ++c) {
        us4 wv;
        #pragma unroll
        for (int r = 0; r < 4; ++r) wv[r] = f2b(b2f(pv[r][c]) * av4[r][c]);
        const int rowm = m4 + c;
        const int off = (((nn4 >> 3) ^ (rowm & 7)) * 8) + (nn4 & 4);
        *(us4*)&As[0][(k1s * 32 + rowm) * 64 + off] = wv;
    }

    for (int it = 0; it < 32; ++it) {
        __syncthreads();
        const int cur = it & 1;
        if (it < 31) {                  // prefetch next n-chunk (raw loads only)
            const int nc = (it + 1) * 64;
            #pragma unroll
            for (int p = 0; p < 6; ++p) {
                const int row = (w * 6 + p) * 8 + l3;
                xv[p] = *(const us8*)&xbT[((size_t)b * FT + row) * NN + nc + l7 * 8];
            }
            #pragma unroll
            for (int r = 0; r < 4; ++r) {
                const int nn = nc + nn4 + r;
                pv[r]  = *(const us4*)&Pk[(size_t)nn * NN + m0 + m4];
                av4[r] = *(const f32x4*)&attb[(size_t)nn * NN + m0 + m4];
            }
        }
        #pragma unroll
        for (int s = 0; s < 2; ++s) {
            short8 a[2], bb[6];
            #pragma unroll
            for (int i = 0; i < 2; ++i) {
                const int row = i * 16 + l15;
                a[i] = *(const short8*)&As[cur][(k1 * 32 + row) * 64 + (((s * 4 + q) ^ l7) * 8)];
            }
            #pragma unroll
            for (int t = 0; t < 6; ++t) {
                const int col = ft0 + t * 16 + l15;
                const int u = ((s * 4 + q) ^ (col & 7)) * 8;
                bb[t] = *(const short8*)&Xs[cur][col * 64 + u];
            }
            #pragma unroll
            for (int i = 0; i < 2; ++i)
                #pragma unroll
                for (int t = 0; t < 6; ++t)
                    acc[i][t] = __builtin_amdgcn_mfma_f32_16x16x32_bf16(a[i], bb[t], acc[i][t], 0, 0, 0);
        }
        if (it < 31) {                  // Hadamard + write to other buffer
            const int nxt = cur ^ 1;
            #pragma unroll
            for (int p = 0; p < 6; ++p) {
                const int row = (w * 6 + p) * 8 + l3;
                *(us8*)&Xs[nxt][row * 64 + (l7 ^ l3) * 8] = xv[p];
            }
            #pragma unroll
            for (int c = 0; c < 4; ++c) {
                us4 wv;
                #pragma unroll
                for (int r = 0; r < 4; ++r) wv[r] = f2b(b2f(pv[r][c]) * av4[r][c]);
                const int rowm = m4 + c;
                const int off = (((nn4 >> 3) ^ (rowm & 7)) * 8) + (nn4 & 4);
                *(us4*)&As[nxt][(k1s * 32 + rowm) * 64 + off] = wv;
            }
        }
    }
    float* __restrict__ op = rhs + ((size_t)(k1 * BATCH + b)) * NN * FT;
    #pragma unroll
    for (int i = 0; i < 2; ++i)
        #pragma unroll
        for (int t = 0; t < 6; ++t)
            #pragma unroll
            for (int r = 0; r < 4; ++r) {
                const int mg = m0 + i * 16 + q * 4 + r;
                const int ftg = ft0 + t * 16 + l15;
                op[(size_t)mg * FT + ftg] = acc[i][t][r];
            }
}

// ---------------------------------------------------------------------------
// Phase 4: out[b,m,o,t] = relu( th0.(att[b,m,m]*x[b,m]) + th1.rhs1 + th2.rhs2 )
// ---------------------------------------------------------------------------
__global__ __launch_bounds__(128)
void k_out(const float* __restrict__ x, const float* __restrict__ att,
           const float* __restrict__ theta, const float* __restrict__ rhs,
           float* __restrict__ out) {
    const int m = blockIdx.x & (NN - 1);
    const int b = blockIdx.x >> 11;
    __shared__ float xr[FT], r1[FT], r2[FT];
    __shared__ float th[3 * FIN * FOUT];
    const int tid = threadIdx.x;

    const float* __restrict__ xb = x + ((size_t)b * NN + m) * FT;
    const float* __restrict__ p1 = rhs + ((size_t)0 * BATCH + b) * NN * FT + (size_t)m * FT;
    const float* __restrict__ p2 = rhs + ((size_t)1 * BATCH + b) * NN * FT + (size_t)m * FT;
    const float a0 = att[((size_t)b * NN + m) * NN + m];

    for (int i = tid; i < FT; i += 128) {
        xr[i] = xb[i] * a0;
        r1[i] = p1[i];
        r2[i] = p2[i];
    }
    for (int i = tid; i < 3 * FIN * FOUT; i += 128) th[i] = theta[i];
    __syncthreads();

    float* __restrict__ ob = out + ((size_t)b * NN + m) * OT;
    for (int idx = tid; idx < OT; idx += 128) {
        const int o = idx / TT, t = idx % TT;
        float acc = 0.0f;
        #pragma unroll
        for (int f = 0; f < FIN; ++f) {
            const int ft = f * TT + t;
            acc += th[f * FOUT + o] * xr[ft];
            acc += th[512 + f * FOUT + o] * r1[ft];
            acc += th[1024 + f * FOUT + o] * r2[ft];
        }
        ob[idx] = fmaxf(acc, 0.0f);
    }
}

// ---------------------------------------------------------------------------
extern "C" void kernel_launch(void* const* d_in, const int* in_sizes, int n_in,
                              void* d_out, int out_size, void* d_ws, size_t ws_size,
                              hipStream_t stream) {
    const float* x     = (const float*)d_in[0]; // (B,N,F_in,T) fp32
    const float* att   = (const float*)d_in[1]; // (B,N,N) fp32
    const float* E     = (const float*)d_in[2]; // (N,16) fp32
    const float* theta = (const float*)d_in[3]; // (K,F_in,F_out) fp32
    float* out = (float*)d_out;                 // (B,N,F_out,T) fp32

    // Workspace: Sb | SbT | T2b (bf16 N*N each) | xbT (bf16 B*FT*N) | rhs (fp32)
    ushort_t* Sb  = (ushort_t*)d_ws;
    ushort_t* SbT = Sb  + (size_t)NN * NN;
    ushort_t* T2b = SbT + (size_t)NN * NN;
    ushort_t* xbT = T2b + (size_t)NN * NN;
    float*    rhs = (float*)(xbT + (size_t)BATCH * FT * NN);   // ~54 MB total

    k_supports<<<NN, 256, 0, stream>>>(E, Sb);
    k_pack_st<<<dim3(32, 32), 256, 0, stream>>>(Sb, SbT);
    k_pack_x<<<dim3(32, BATCH), 256, 0, stream>>>(x, xbT);
    k_t2<<<dim3(32, 32), 256, 0, stream>>>(Sb, SbT, T2b);
    k_rhs<<<dim3(64, BATCH), 256, 0, stream>>>(Sb, T2b, att, xbT, rhs);
    k_out<<<BATCH * NN, 128, 0, stream>>>(x, att, theta, rhs, out);
}